// Round 5
// baseline (224.490 us; speedup 1.0000x reference)
//
#include <hip/hip_runtime.h>

typedef __attribute__((ext_vector_type(8))) short bf16x8;
typedef __attribute__((ext_vector_type(8))) unsigned short ushort8;
typedef __attribute__((ext_vector_type(4))) float f32x4;

#define SCALEf 2.0f
#define EPSf 1e-5f

// ws layout:
//   floats [0, 2176)    : accum[zb=17][n=16][co=8]
//   floats [2176, 2192) : Aaff[8], Baff[8]
//   bytes  [32768, +24576) : wfrag bf16 [12 g][2 zsub][64 lane][8 ci]
#define WS_AFF 2176
#define WS_WF_BYTE 32768

__device__ __forceinline__ unsigned short bfr(float f) {   // f32 -> bf16 RNE
    unsigned u = __float_as_uint(f);
    return (unsigned short)((u + 0x7FFFu + ((u >> 16) & 1u)) >> 16);
}

// XOR-swizzle: mix addr bits 7-9 into 4-6; bijective within each 128-B block,
// preserves 16-B alignment (b128-legal). Same function on write and read.
__device__ __forceinline__ int SW(int a) { return a ^ ((a >> 3) & 0x70); }

// ---- pass 1: zero accum, fold affine, build weight fragments ----
// taps: tzext 0..3, tyext 0..3, tx 0..2 (48 taps, 12 groups of 4)
__global__ void prep_kernel(const float* __restrict__ w, const float* __restrict__ bias,
                            const float* __restrict__ mean, const float* __restrict__ var,
                            const float* __restrict__ gamma, const float* __restrict__ beta,
                            float* __restrict__ wsf, unsigned short* __restrict__ wfrag) {
    int gid = blockIdx.x * 256 + threadIdx.x;
    if (gid < 2176) wsf[gid] = 0.0f;
    if (gid >= 2176 && gid < 2184) {
        int co = gid - 2176;
        float inv = rsqrtf(var[co] + EPSf);
        wsf[WS_AFF + co] = SCALEf * inv * gamma[co];
        wsf[WS_AFF + 8 + co] = (bias[co] * SCALEf - mean[co]) * inv * gamma[co] + beta[co];
    }
    int i = gid - 4096;
    if (i >= 0 && i < 12288) {                // wfrag[g][zsub][lane][ci]
        int j = i & 7;                        // ci
        int l = (i >> 3) & 63;                // lane
        int gz = i >> 9;                      // 0..23
        int g = gz >> 1, zsub = gz & 1;
        int col = l & 15, chunk = l >> 4;
        int co = col & 7, ysub = col >> 3;
        int tap = g * 4 + chunk;              // 0..47
        int tz = tap / 12, ty = (tap % 12) / 3, tx = tap % 3;
        int ez = tz - zsub, ey = ty - ysub;
        float v = 0.0f;
        if (ez >= 0 && ez <= 2 && ey >= 0 && ey <= 2)
            v = w[(co * 8 + j) * 27 + (2 - ez) * 9 + (2 - ey) * 3 + (2 - tx)];
        wfrag[i] = bfr(v);
    }
}

// ---- pass 2: fused convert+stage + implicit-GEMM conv + affine + relu + sums ----
// block: 4 zo x 8 yo x 66 x ; slab [z 6][y 10][x 68][ci 8] bf16 (swizzled)
__global__ __launch_bounds__(256) void conv_kernel(const float* __restrict__ x,
                                                   const float* __restrict__ wsf,
                                                   const unsigned short* __restrict__ wfrag,
                                                   float* __restrict__ accum) {
    __shared__ unsigned short slab[60 * 68 * 8];   // 65280 B
    __shared__ float red[4][8];

    const int tid = threadIdx.x;
    const int lane = tid & 63, wave = tid >> 6;
    const int col = lane & 15, chunk = lane >> 4;
    const int ybase = blockIdx.x * 8;           // 0,8,...,64
    const int zo0 = blockIdx.y * 4;             // 0,4,...,64
    const int n = blockIdx.z;
    const bool interior = (blockIdx.x < 8) && (blockIdx.y < 16);

    // B fragments: 12 groups x 2 zsub
    bf16x8 b0[12], b1[12];
#pragma unroll
    for (int g = 0; g < 12; g++) {
        b0[g] = *(const bf16x8*)(wfrag + ((g * 2 + 0) * 64 + lane) * 8);
        b1[g] = *(const bf16x8*)(wfrag + ((g * 2 + 1) * 64 + lane) * 8);
    }

    const float Aaff = wsf[WS_AFF + (col & 7)];
    const float Baff = wsf[WS_AFF + 8 + (col & 7)];

    int cg[12];                                 // per-lane tap byte offset in slab
#pragma unroll
    for (int g = 0; g < 12; g++) {
        int tap = g * 4 + chunk;
        int tz = tap / 12, ty = (tap % 12) / 3, tx = tap % 3;
        cg[g] = ((tz * 10 + ty) * 68 + tx) * 16;
    }

    char* slabc = (char*)slab;

    // ---- stage: read x fp32 directly, convert to bf16 channels-last, swizzled ----
    {
        const float* xn = x + ((size_t)n << 21);
        for (int u = tid; u < 960; u += 256) {  // 60 rows x 16 x-quads
            int k = u & 15, row = u >> 4;       // row = z*10 + y
            int z = row / 10, yy = row - z * 10;
            int zi = zo0 - 2 + z, yi = ybase - 2 + yy;
            int base = (row * 68 + 2 + k * 4) * 16;
            if ((unsigned)zi < 64u && (unsigned)yi < 64u) {
                const float* xp = xn + ((zi * 64 + yi) * 64 + k * 4);
                ushort8 o0, o1, o2, o3;
#pragma unroll
                for (int ci = 0; ci < 8; ci++) {
                    float4 v = *(const float4*)(xp + ((size_t)ci << 18));
                    o0[ci] = bfr(v.x); o1[ci] = bfr(v.y);
                    o2[ci] = bfr(v.z); o3[ci] = bfr(v.w);
                }
                *(ushort8*)(slabc + SW(base))      = o0;
                *(ushort8*)(slabc + SW(base + 16)) = o1;
                *(ushort8*)(slabc + SW(base + 32)) = o2;
                *(ushort8*)(slabc + SW(base + 48)) = o3;
            } else {
                ushort8 zz = {0, 0, 0, 0, 0, 0, 0, 0};
                *(ushort8*)(slabc + SW(base))      = zz;
                *(ushort8*)(slabc + SW(base + 16)) = zz;
                *(ushort8*)(slabc + SW(base + 32)) = zz;
                *(ushort8*)(slabc + SW(base + 48)) = zz;
            }
        }
        // x-halo pad zeros: 60 rows x {0,1,66,67}
        if (tid < 240) {
            int row = tid >> 2, q = tid & 3;
            int xpos = (q < 2) ? q : 64 + q;    // 0,1,66,67
            int a = (row * 68 + xpos) * 16;
            ushort8 zz = {0, 0, 0, 0, 0, 0, 0, 0};
            *(ushort8*)(slabc + SW(a)) = zz;
        }
    }
    __syncthreads();

    // ---- main: M = 528 base pts (zt2 x yt4 x 66) = 33 tiles; 12 K-groups x 2 MFMA ----
    float sum = 0.0f;
    for (int t = wave; t < 33; t += 4) {
        int p = t * 16 + col;                   // 0..527, always valid
        int zt = (p >= 264) ? 1 : 0;
        int rem = p - zt * 264;
        int yt = rem / 66;
        int xo = rem - yt * 66;
        int abase = ((zt * 20 + yt * 2) * 68 + xo) * 16;
        f32x4 acc0 = {0.f, 0.f, 0.f, 0.f};
        f32x4 acc1 = {0.f, 0.f, 0.f, 0.f};
#pragma unroll
        for (int g = 0; g < 12; g++) {
            int lin = abase + cg[g];
            bf16x8 a = *(const bf16x8*)(slabc + SW(lin));
            acc0 = __builtin_amdgcn_mfma_f32_16x16x32_bf16(a, b0[g], acc0, 0, 0, 0);
            acc1 = __builtin_amdgcn_mfma_f32_16x16x32_bf16(a, b1[g], acc1, 0, 0, 0);
        }
        if (interior) {                         // no masks, no divisions
#pragma unroll
            for (int j = 0; j < 4; j++) {
                sum += fmaxf(fmaf(Aaff, acc0[j], Baff), 0.0f);
                sum += fmaxf(fmaf(Aaff, acc1[j], Baff), 0.0f);
            }
        } else {
#pragma unroll
            for (int j = 0; j < 4; j++) {
                int m = t * 16 + chunk * 4 + j; // C/D row -> base point
                int mzt = (m >= 264) ? 1 : 0;
                int mrem = m - mzt * 264;
                int myt = mrem / 66;
                int yo = ybase + myt * 2 + (col >> 3);
                int zoA = zo0 + mzt * 2;
                bool vy = (yo < 66);
                float v0 = fmaxf(fmaf(Aaff, acc0[j], Baff), 0.0f);
                float v1 = fmaxf(fmaf(Aaff, acc1[j], Baff), 0.0f);
                sum += (vy && (zoA < 66)) ? v0 : 0.0f;
                sum += (vy && (zoA + 1 < 66)) ? v1 : 0.0f;
            }
        }
    }

    // reduce lanes sharing co (= lane&7): xor bits 3,4,5
    sum += __shfl_xor(sum, 8, 64);
    sum += __shfl_xor(sum, 16, 64);
    sum += __shfl_xor(sum, 32, 64);
    if (lane < 8) red[wave][lane] = sum;
    __syncthreads();
    if (tid < 8) {
        float s = red[0][tid] + red[1][tid] + red[2][tid] + red[3][tid];
        atomicAdd(&accum[blockIdx.y * 128 + n * 8 + tid], s);
    }
}

__global__ void finalize_kernel(const float* __restrict__ accum, float* __restrict__ out) {
    int t = threadIdx.x;                        // 128 = n*8+co
    float s = 0.0f;
    for (int zb = 0; zb < 17; zb++) s += accum[zb * 128 + t];
    out[t] = s * (1.0f / (66.0f * 66.0f * 66.0f));
}

extern "C" void kernel_launch(void* const* d_in, const int* in_sizes, int n_in,
                              void* d_out, int out_size, void* d_ws, size_t ws_size,
                              hipStream_t stream) {
    const float* x      = (const float*)d_in[0];
    const float* weight = (const float*)d_in[1];
    const float* bias   = (const float*)d_in[2];
    const float* rmean  = (const float*)d_in[3];
    const float* rvar   = (const float*)d_in[4];
    const float* gamma  = (const float*)d_in[5];
    const float* beta   = (const float*)d_in[6];

    float* wsf = (float*)d_ws;
    unsigned short* wfrag = (unsigned short*)((char*)d_ws + WS_WF_BYTE);
    float* out = (float*)d_out;

    prep_kernel<<<64, 256, 0, stream>>>(weight, bias, rmean, rvar, gamma, beta, wsf, wfrag);
    conv_kernel<<<dim3(9, 17, 16), 256, 0, stream>>>(x, wsf, wfrag, wsf);
    finalize_kernel<<<1, 128, 0, stream>>>(wsf, out);
}